// Round 16
// baseline (36.810 us; speedup 1.0000x reference)
//
#include <hip/hip_runtime.h>
#include <hip/hip_bf16.h>

#define NH 32          // heads
#define NV 1537        // edge_enc_w rows
#define ND 20          // MULTI_HOP_MAX_DIST
#define NB 16          // batch
#define NN 64          // nodes

// ws tables (both fp8 e4m3, x256 scale), both gathered from global (L1/L2-hot):
//  enc: contiguous 32B rows (8 u32)   -> A-fragments, direct MFMA feed
//  Wd8: [d][h][32B k-row]             -> B-fragments
#define ENC_U32 (NV*8)                   // 12,296 u32 = 49,184 B
#define WD8_U32 (ND*NH*8)                // 5,120 u32 = 20,480 B

#define CVT1_BLOCKS ((ENC_U32 + 255)/256)  // 49
#define CVT2_BLOCKS (WD8_U32/256)          // 20
#define BORDER_N (NB*NH*65 + NB*NH*64)     // 66048
#define BBLOCKS ((BORDER_N + 255)/256)     // 258

// main LDS (bytes): sdx 64x168 = 10,752 | spos 256  -> occupancy VGPR-bound
#define LDS_SDX  0
#define LDS_SPOS 10752
#define MAIN_LDS 11008

typedef unsigned int   u32;
typedef unsigned short u16;
typedef __attribute__((ext_vector_type(4))) float        f32x4;
typedef __attribute__((ext_vector_type(4))) int          v4i;

// ---- fp8 e4m3 encode (proven R7-R15) ----
__device__ __forceinline__ u32 f32x4_to_fp8(float a0, float a1, float a2, float a3) {
#if __has_builtin(__builtin_amdgcn_cvt_pk_fp8_f32)
    u32 u = __builtin_amdgcn_cvt_pk_fp8_f32(a0, a1, 0u, false);
    u     = __builtin_amdgcn_cvt_pk_fp8_f32(a2, a3, u,  true);
    return u;
#else
    u32 lo, hi;
    asm("v_cvt_pk_fp8_f32 %0, %1, %2" : "=v"(lo) : "v"(a0), "v"(a1));
    asm("v_cvt_pk_fp8_f32 %0, %1, %2" : "=v"(hi) : "v"(a2), "v"(a3));
    return (lo & 0xffffu) | (hi << 16);
#endif
}

// ---------------- Kernel 1: enc->fp8 (32B rows), Wd->fp8 [d][h][k], borders --------
__global__ void __launch_bounds__(256)
prep_kernel(const float* __restrict__ enc,     // (1537,32)
            const float* __restrict__ wdis,    // (20,32,32)
            const float* __restrict__ ab,      // (B,65,65)
            const float* __restrict__ tokw,    // (32,)
            u32* __restrict__ tab,             // [ENC_U32 | WD8_U32] in ws
            float* __restrict__ out) {         // (B,32,65,65)
    int blk = blockIdx.x, tid = threadIdx.x;
    if (blk < CVT1_BLOCKS) {
        int o = blk * 256 + tid;
        if (o < ENC_U32) {
            float4 e = *(const float4*)(enc + (size_t)o * 4);
            tab[o] = f32x4_to_fp8(e.x * 256.f, e.y * 256.f,
                                  e.z * 256.f, e.w * 256.f);
        }
    } else if (blk < CVT1_BLOCKS + CVT2_BLOCKS) {
        int o = (blk - CVT1_BLOCKS) * 256 + tid;   // < 5120
        int d = o >> 8, rem = o & 255;
        int h = rem >> 3, k4 = rem & 7;            // 4 k per u32
        const float* ws = wdis + d * 1024 + h;     // wdis[d][k][h]
        tab[ENC_U32 + (d * 32 + h) * 8 + k4] =
            f32x4_to_fp8(ws[(k4 * 4 + 0) * 32] * 256.f,
                         ws[(k4 * 4 + 1) * 32] * 256.f,
                         ws[(k4 * 4 + 2) * 32] * 256.f,
                         ws[(k4 * 4 + 3) * 32] * 256.f);
    } else {
        int t = (blk - CVT1_BLOCKS - CVT2_BLOCKS) * 256 + tid;
        const int nA = NB * NH * 65;           // row 0, all j
        if (t < nA) {
            int j = t % 65; int bh = t / 65; int h = bh & 31; int b = bh >> 5;
            __builtin_nontemporal_store(2.0f * ab[b * 4225 + j] + tokw[h],
                &out[(((size_t)b * NH + h) * 65 + 0) * 65 + j]);
        } else {
            t -= nA;                           // col 0, i >= 1
            if (t >= NB * NH * 64) return;
            int i = (t % 64) + 1; int bh = t / 64; int h = bh & 31; int b = bh >> 5;
            __builtin_nontemporal_store(2.0f * ab[b * 4225 + i * 65] + tokw[h],
                &out[(((size_t)b * NH + h) * 65 + i) * 65 + 0]);
        }
    }
}

// ---------------- Kernel 2: global-gather fp8 MFMA, high occupancy ----------------
// 1024 blocks (one i-row = 64 cells) x 256 thr (4 waves), target 6 blocks/CU
// (24 waves/CU). No enc staging: A-rows gathered straight from the 49KB
// L1/L2-hot global table as b64; B from 20KB L1-hot table; 6 indep acc chains.
__global__ void __launch_bounds__(256, 6)
main_kernel(const float* __restrict__ ab,      // (B,65,65)
            const int*   __restrict__ spos,    // (B,64,64)
            const int*   __restrict__ eidx,    // (B,64,64,20,3)
            const float* __restrict__ mask2d,  // (B,)
            const float* __restrict__ spw,     // (512,32)
            const u32*   __restrict__ tab,     // [enc fp8 | Wd8 fp8] (ws)
            float*       __restrict__ out) {   // (B,32,65,65)
    extern __shared__ __align__(16) char dyn[];
    u16* sdx   = (u16*)(dyn + LDS_SDX);        // [64 cells][84 u16]
    int* sposL = (int*)(dyn + LDS_SPOS);

    int tid = threadIdx.x, blk = blockIdx.x;   // 1024 blocks
    int b = blk >> 6, i = blk & 63;

    // --- stage edge indices: 64 cells x 60 -> sdx[cell][d*4+f], stride 84 ---
    const v4i* ep4 = (const v4i*)(eidx + (size_t)blk * 3840);
    for (int t = tid; t < 960; t += 256) {
        v4i q = __builtin_nontemporal_load(ep4 + t);
        int base = t * 4;
#pragma unroll
        for (int c = 0; c < 4; ++c) {
            int f2 = base + c;
            int cell = f2 / 60, pos = f2 - cell * 60;
            int d = pos / 3, f = pos - d * 3;
            int val = (c == 0) ? q.x : (c == 1) ? q.y : (c == 2) ? q.z : q.w;
            sdx[cell * 84 + d * 4 + f] = (u16)val;
        }
    }
    if (tid < 64) sposL[tid] = spos[blk * 64 + tid];
    __syncthreads();

    // --- compute: wave wv owns cells wv*16 .. wv*16+15 ---
    int wv = tid >> 6, l = tid & 63;
    int c16 = l & 15, g = l >> 4;              // A row / B col, k-group

    const char* encG = (const char*)tab + g * 8;   // + row*32 per gather (global)
    const u16* sd = sdx + (wv * 16 + c16) * 84;
    const u32* wdg = tab + ENC_U32;            // global fp8 Wd, L1-hot

    f32x4 acc[2][3] = {};                      // [head-half][f], static idx

#pragma unroll 4
    for (int d = 0; d < ND; ++d) {
        long bf0 = *(const long*)(wdg + (d * 32 + c16) * 8 + g * 2);
        long bf1 = *(const long*)(wdg + (d * 32 + c16 + 16) * 8 + g * 2);
        ushort4 q = *(const ushort4*)(sd + d * 4);
        long a0 = *(const long*)(encG + ((u32)q.x << 5));
        long a1 = *(const long*)(encG + ((u32)q.y << 5));
        long a2 = *(const long*)(encG + ((u32)q.z << 5));
        acc[0][0] = __builtin_amdgcn_mfma_f32_16x16x32_fp8_fp8(a0, bf0, acc[0][0], 0, 0, 0);
        acc[1][0] = __builtin_amdgcn_mfma_f32_16x16x32_fp8_fp8(a0, bf1, acc[1][0], 0, 0, 0);
        acc[0][1] = __builtin_amdgcn_mfma_f32_16x16x32_fp8_fp8(a1, bf0, acc[0][1], 0, 0, 0);
        acc[1][1] = __builtin_amdgcn_mfma_f32_16x16x32_fp8_fp8(a1, bf1, acc[1][1], 0, 0, 0);
        acc[0][2] = __builtin_amdgcn_mfma_f32_16x16x32_fp8_fp8(a2, bf0, acc[0][2], 0, 0, 0);
        acc[1][2] = __builtin_amdgcn_mfma_f32_16x16x32_fp8_fp8(a2, bf1, acc[1][2], 0, 0, 0);
    }
    f32x4 acc0 = acc[0][0] + acc[0][1] + acc[0][2];
    f32x4 acc1 = acc[1][0] + acc[1][1] + acc[1][2];

    __syncthreads();                           // sdx dead; alias comb over it
    float* comb = (float*)(dyn + LDS_SDX);     // [64 cells][33] = 8,448 B
    float m = mask2d[b];
#pragma unroll
    for (int r = 0; r < 4; ++r) {
        int cell = wv * 16 + g * 4 + r;        // D: row=(l>>4)*4+r, col=l&15
        int s = sposL[cell];
        int sp = (s == 0) ? 1 : s;
        sp = (sp > 1) ? sp - 1 : sp;
        sp = (sp > ND) ? ND : sp;
        float esc = m / (196608.0f * (float)sp);   // /(256*256) /3sp
        float spbL = spw[s * NH + c16];
        float spbH = spw[s * NH + c16 + 16];
        comb[cell * 33 + c16]      = spbL * m + acc0[r] * esc;
        comb[cell * 33 + c16 + 16] = spbH * m + acc1[r] * esc;
    }
    __syncthreads();

    // --- write out: 32 h x 64 j for row i, 256B-coalesced over j ---
#pragma unroll
    for (int w = 0; w < 8; ++w) {
        int idx = w * 256 + tid;               // [0, 2048)
        int j = idx & 63, h = idx >> 6;
        float av = ab[(b * 65 + i + 1) * 65 + (j + 1)];
        __builtin_nontemporal_store(2.0f * av + comb[j * 33 + h],
            &out[(((size_t)b * NH + h) * 65 + i + 1) * 65 + (j + 1)]);
    }
}

extern "C" void kernel_launch(void* const* d_in, const int* in_sizes, int n_in,
                              void* d_out, int out_size, void* d_ws, size_t ws_size,
                              hipStream_t stream) {
    const float* attn_bias   = (const float*)d_in[0];
    const int*   spatial_pos = (const int*)  d_in[1];
    // d_in[2] = x (unused), d_in[4] = attn_edge_type (unused)
    const int*   edge_input  = (const int*)  d_in[3];
    const float* mask_2d     = (const float*)d_in[5];
    const float* edge_enc_w  = (const float*)d_in[6];
    const float* edge_dis_w  = (const float*)d_in[7];
    const float* spatial_w   = (const float*)d_in[8];
    const float* token_w     = (const float*)d_in[9];
    float* out = (float*)d_out;
    u32* tab = (u32*)d_ws;                 // 49,184 + 20,480 B

    // Kernel 1: fp8 converts + borders
    prep_kernel<<<CVT1_BLOCKS + CVT2_BLOCKS + BBLOCKS, 256, 0, stream>>>(
        edge_enc_w, edge_dis_w, attn_bias, token_w, tab, out);
    // Kernel 2: global-gather fp8 MFMA (LDS = 11,008 B, high occupancy)
    main_kernel<<<NB * NN, 256, MAIN_LDS, stream>>>(attn_bias, spatial_pos, edge_input,
                                                    mask_2d, spatial_w, tab, out);
}

// Round 17
// 31.051 us; speedup vs baseline: 1.1855x; 1.1855x over previous
//
#include <hip/hip_runtime.h>
#include <hip/hip_bf16.h>

#define NH 32          // heads
#define NV 1537        // edge_enc_w rows
#define ND 20          // MULTI_HOP_MAX_DIST
#define NB 16          // batch
#define NN 64          // nodes

// ws tables (both fp8 e4m3, x256 scale):
//  enc: padded 40B rows (10 u32, 8 used)  -> LDS-gathered, bank-spread
//  Wd8: [d][h][32B k-row]                 -> L1-resident, B-fragments
#define ENCP_U32 (NV*10)                 // 15,370 u32 = 61,480 B
#define WD8_U32  (ND*NH*8)               // 5,120 u32 = 20,480 B

#define CVT1_BLOCKS ((NV*8 + 255)/256)   // 49
#define CVT2_BLOCKS (WD8_U32/256)        // 20

// main LDS (bytes): enc 61,480 | sdx 64x168 = 10,752 | spos 256
#define LDS_ENC  0
#define LDS_SDX  61480
#define LDS_SPOS 72232
#define MAIN_LDS 72488                   // -> 2 blocks/CU

typedef unsigned int   u32;
typedef unsigned short u16;
typedef __attribute__((ext_vector_type(4))) float        f32x4;
typedef __attribute__((ext_vector_type(4))) unsigned int u32x4;
typedef __attribute__((ext_vector_type(4))) int          v4i;

// ---- fp8 e4m3 encode (proven R7-R16) ----
__device__ __forceinline__ u32 f32x4_to_fp8(float a0, float a1, float a2, float a3) {
#if __has_builtin(__builtin_amdgcn_cvt_pk_fp8_f32)
    u32 u = __builtin_amdgcn_cvt_pk_fp8_f32(a0, a1, 0u, false);
    u     = __builtin_amdgcn_cvt_pk_fp8_f32(a2, a3, u,  true);
    return u;
#else
    u32 lo, hi;
    asm("v_cvt_pk_fp8_f32 %0, %1, %2" : "=v"(lo) : "v"(a0), "v"(a1));
    asm("v_cvt_pk_fp8_f32 %0, %1, %2" : "=v"(hi) : "v"(a2), "v"(a3));
    return (lo & 0xffffu) | (hi << 16);
#endif
}

// ---------------- Kernel 1 (69 blocks): enc->fp8 padded, Wd->fp8 [d][h][k] ----------
__global__ void __launch_bounds__(256)
prep_kernel(const float* __restrict__ enc,     // (1537,32)
            const float* __restrict__ wdis,    // (20,32,32)
            u32* __restrict__ tab) {           // [ENCP_U32 | WD8_U32] in ws
    int blk = blockIdx.x, tid = threadIdx.x;
    if (blk < CVT1_BLOCKS) {
        int o = blk * 256 + tid;               // u32: row = o>>3, slot = o&7
        if (o < NV * 8) {
            float4 e = *(const float4*)(enc + (size_t)o * 4);
            tab[(o >> 3) * 10 + (o & 7)] = f32x4_to_fp8(e.x * 256.f, e.y * 256.f,
                                                        e.z * 256.f, e.w * 256.f);
        }
    } else {
        int o = (blk - CVT1_BLOCKS) * 256 + tid;   // < 5120
        int d = o >> 8, rem = o & 255;
        int h = rem >> 3, k4 = rem & 7;            // 4 k per u32
        const float* ws = wdis + d * 1024 + h;     // wdis[d][k][h]
        tab[ENCP_U32 + (d * 32 + h) * 8 + k4] =
            f32x4_to_fp8(ws[(k4 * 4 + 0) * 32] * 256.f,
                         ws[(k4 * 4 + 1) * 32] * 256.f,
                         ws[(k4 * 4 + 2) * 32] * 256.f,
                         ws[(k4 * 4 + 3) * 32] * 256.f);
    }
}

// ---------------- Kernel 2: pure-fp8 MFMA contraction + borders ----------------
// 1024 blocks (one i-row = 64 cells) x 256 thr (4 waves), 2 blocks/CU.
// Wave owns a 16-cell tile. K = (d,f,k) = 1920: A = gathered enc-fp8 rows
// (ds_read_b64, NO decode), B = Wd8 from L1. 6 independent acc chains.
// Borders folded in: each block writes its row's col-0; i==0 blocks write row 0.
__global__ void __launch_bounds__(256, 2)
main_kernel(const float* __restrict__ ab,      // (B,65,65)
            const int*   __restrict__ spos,    // (B,64,64)
            const int*   __restrict__ eidx,    // (B,64,64,20,3)
            const float* __restrict__ mask2d,  // (B,)
            const float* __restrict__ spw,     // (512,32)
            const float* __restrict__ tokw,    // (32,)
            const u32*   __restrict__ tab,     // [enc fp8 pad | Wd8] (ws)
            float*       __restrict__ out) {   // (B,32,65,65)
    extern __shared__ __align__(16) char dyn[];
    u16* sdx   = (u16*)(dyn + LDS_SDX);        // [64 cells][84 u16]
    int* sposL = (int*)(dyn + LDS_SPOS);

    int tid = threadIdx.x, blk = blockIdx.x;   // 1024 blocks
    int b = blk >> 6, i = blk & 63;

    // --- stage padded enc fp8 into LDS (linear, L2-hot): 61,480 B ---
    {
        const u32x4* g4 = (const u32x4*)tab;
        u32x4* s4 = (u32x4*)(dyn + LDS_ENC);
        for (int p = tid; p < 3842; p += 256) s4[p] = g4[p];
        if (tid < 2) ((u32*)(dyn + LDS_ENC))[15368 + tid] = tab[15368 + tid];
    }
    // --- stage edge indices: 64 cells x 60 -> sdx[cell][d*4+f], stride 84 ---
    const v4i* ep4 = (const v4i*)(eidx + (size_t)blk * 3840);
    for (int t = tid; t < 960; t += 256) {
        v4i q = __builtin_nontemporal_load(ep4 + t);
        int base = t * 4;
#pragma unroll
        for (int c = 0; c < 4; ++c) {
            int f2 = base + c;
            int cell = f2 / 60, pos = f2 - cell * 60;
            int d = pos / 3, f = pos - d * 3;
            int val = (c == 0) ? q.x : (c == 1) ? q.y : (c == 2) ? q.z : q.w;
            sdx[cell * 84 + d * 4 + f] = (u16)val;
        }
    }
    if (tid < 64) sposL[tid] = spos[blk * 64 + tid];
    __syncthreads();

    // --- compute: wave wv owns cells wv*16 .. wv*16+15 ---
    int wv = tid >> 6, l = tid & 63;
    int c16 = l & 15, g = l >> 4;              // A row / B col, k-group

    const char* encB = dyn + LDS_ENC + g * 8;  // + row*40 per gather
    const u16* sd = (const u16*)(dyn + LDS_SDX) + (wv * 16 + c16) * 84;
    const u32* wdg = tab + ENCP_U32;           // global fp8 Wd, L1-hot

    f32x4 acc[2][3] = {};                      // [head-half][f], static idx

#pragma unroll
    for (int d = 0; d < ND; ++d) {
        long bf0 = *(const long*)(wdg + (d * 32 + c16) * 8 + g * 2);
        long bf1 = *(const long*)(wdg + (d * 32 + c16 + 16) * 8 + g * 2);
        ushort4 q = *(const ushort4*)(sd + d * 4);
        long a0 = *(const long*)(encB + (u32)q.x * 40u);
        long a1 = *(const long*)(encB + (u32)q.y * 40u);
        long a2 = *(const long*)(encB + (u32)q.z * 40u);
        acc[0][0] = __builtin_amdgcn_mfma_f32_16x16x32_fp8_fp8(a0, bf0, acc[0][0], 0, 0, 0);
        acc[1][0] = __builtin_amdgcn_mfma_f32_16x16x32_fp8_fp8(a0, bf1, acc[1][0], 0, 0, 0);
        acc[0][1] = __builtin_amdgcn_mfma_f32_16x16x32_fp8_fp8(a1, bf0, acc[0][1], 0, 0, 0);
        acc[1][1] = __builtin_amdgcn_mfma_f32_16x16x32_fp8_fp8(a1, bf1, acc[1][1], 0, 0, 0);
        acc[0][2] = __builtin_amdgcn_mfma_f32_16x16x32_fp8_fp8(a2, bf0, acc[0][2], 0, 0, 0);
        acc[1][2] = __builtin_amdgcn_mfma_f32_16x16x32_fp8_fp8(a2, bf1, acc[1][2], 0, 0, 0);
    }
    f32x4 acc0 = acc[0][0] + acc[0][1] + acc[0][2];
    f32x4 acc1 = acc[1][0] + acc[1][1] + acc[1][2];

    __syncthreads();                           // sdx dead; alias comb over it
    float* comb = (float*)(dyn + LDS_SDX);     // [64 cells][33] = 8,448 B
    float m = mask2d[b];
#pragma unroll
    for (int r = 0; r < 4; ++r) {
        int cell = wv * 16 + g * 4 + r;        // D: row=(l>>4)*4+r, col=l&15
        int s = sposL[cell];
        int sp = (s == 0) ? 1 : s;
        sp = (sp > 1) ? sp - 1 : sp;
        sp = (sp > ND) ? ND : sp;
        float esc = m / (196608.0f * (float)sp);   // /(256*256) /3sp
        float spbL = spw[s * NH + c16];
        float spbH = spw[s * NH + c16 + 16];
        comb[cell * 33 + c16]      = spbL * m + acc0[r] * esc;
        comb[cell * 33 + c16 + 16] = spbH * m + acc1[r] * esc;
    }
    __syncthreads();

    // --- write out: 32 h x 64 j for row i+1, 256B-coalesced over j ---
#pragma unroll
    for (int w = 0; w < 8; ++w) {
        int idx = w * 256 + tid;               // [0, 2048)
        int j = idx & 63, h = idx >> 6;
        float av = ab[(b * 65 + i + 1) * 65 + (j + 1)];
        __builtin_nontemporal_store(2.0f * av + comb[j * 33 + h],
            &out[(((size_t)b * NH + h) * 65 + i + 1) * 65 + (j + 1)]);
    }

    // --- borders (folded): col-0 of this row; i==0 block also does row 0 ---
    if (tid < NH) {
        float av0 = ab[(b * 65 + i + 1) * 65];
        __builtin_nontemporal_store(2.0f * av0 + tokw[tid],
            &out[(((size_t)b * NH + tid) * 65 + i + 1) * 65 + 0]);
    }
    if (i == 0) {
        for (int t = tid; t < NH * 65; t += 256) {   // 2080 = 32h x 65j
            int h = t / 65, j = t - h * 65;
            __builtin_nontemporal_store(2.0f * ab[b * 4225 + j] + tokw[h],
                &out[(((size_t)b * NH + h) * 65 + 0) * 65 + j]);
        }
    }
}

extern "C" void kernel_launch(void* const* d_in, const int* in_sizes, int n_in,
                              void* d_out, int out_size, void* d_ws, size_t ws_size,
                              hipStream_t stream) {
    const float* attn_bias   = (const float*)d_in[0];
    const int*   spatial_pos = (const int*)  d_in[1];
    // d_in[2] = x (unused), d_in[4] = attn_edge_type (unused)
    const int*   edge_input  = (const int*)  d_in[3];
    const float* mask_2d     = (const float*)d_in[5];
    const float* edge_enc_w  = (const float*)d_in[6];
    const float* edge_dis_w  = (const float*)d_in[7];
    const float* spatial_w   = (const float*)d_in[8];
    const float* token_w     = (const float*)d_in[9];
    float* out = (float*)d_out;
    u32* tab = (u32*)d_ws;                 // 61,480 + 20,480 B

    // Kernel 1: fp8 converts only (69 blocks)
    prep_kernel<<<CVT1_BLOCKS + CVT2_BLOCKS, 256, 0, stream>>>(
        edge_enc_w, edge_dis_w, tab);
    // Kernel 2: pure-fp8 MFMA + folded borders (LDS = 72,488 B, 2 blocks/CU)
    main_kernel<<<NB * NN, 256, MAIN_LDS, stream>>>(attn_bias, spatial_pos, edge_input,
                                                    mask_2d, spatial_w, token_w,
                                                    tab, out);
}

// Round 18
// 22.901 us; speedup vs baseline: 1.6074x; 1.3559x over previous
//
#include <hip/hip_runtime.h>
#include <hip/hip_bf16.h>

#define NH 32          // heads
#define NV 1537        // edge_enc_w rows
#define ND 20          // MULTI_HOP_MAX_DIST
#define NB 16          // batch
#define NN 64          // nodes

// ws tables (both fp8 e4m3, x256 scale):
//  enc: padded 40B rows (10 u32, 8 used)  -> LDS-gathered, bank-spread
//  Wd8: [d][h][32B k-row]                 -> L1-resident, B-fragments
#define ENCP_U32 (NV*10)                 // 15,370 u32 = 61,480 B
#define WD8_U32  (ND*NH*8)               // 5,120 u32 = 20,480 B

#define CVT1_BLOCKS ((NV*8 + 255)/256)   // 49
#define CVT2_BLOCKS (WD8_U32/256)        // 20

#define MAIN_LDS 61480                   // enc only; comb aliases it later

typedef unsigned int   u32;
typedef unsigned short u16;
typedef __attribute__((ext_vector_type(4))) float        f32x4;
typedef __attribute__((ext_vector_type(4))) unsigned int u32x4;
typedef __attribute__((ext_vector_type(4))) int          v4i;

// ---- fp8 e4m3 encode (proven R7-R17) ----
__device__ __forceinline__ u32 f32x4_to_fp8(float a0, float a1, float a2, float a3) {
#if __has_builtin(__builtin_amdgcn_cvt_pk_fp8_f32)
    u32 u = __builtin_amdgcn_cvt_pk_fp8_f32(a0, a1, 0u, false);
    u     = __builtin_amdgcn_cvt_pk_fp8_f32(a2, a3, u,  true);
    return u;
#else
    u32 lo, hi;
    asm("v_cvt_pk_fp8_f32 %0, %1, %2" : "=v"(lo) : "v"(a0), "v"(a1));
    asm("v_cvt_pk_fp8_f32 %0, %1, %2" : "=v"(hi) : "v"(a2), "v"(a3));
    return (lo & 0xffffu) | (hi << 16);
#endif
}

// ---------------- Kernel 1 (69 blocks): enc->fp8 padded, Wd->fp8 [d][h][k] ----------
__global__ void __launch_bounds__(256)
prep_kernel(const float* __restrict__ enc,     // (1537,32)
            const float* __restrict__ wdis,    // (20,32,32)
            u32* __restrict__ tab) {           // [ENCP_U32 | WD8_U32] in ws
    int blk = blockIdx.x, tid = threadIdx.x;
    if (blk < CVT1_BLOCKS) {
        int o = blk * 256 + tid;               // u32: row = o>>3, slot = o&7
        if (o < NV * 8) {
            float4 e = *(const float4*)(enc + (size_t)o * 4);
            tab[(o >> 3) * 10 + (o & 7)] = f32x4_to_fp8(e.x * 256.f, e.y * 256.f,
                                                        e.z * 256.f, e.w * 256.f);
        }
    } else {
        int o = (blk - CVT1_BLOCKS) * 256 + tid;   // < 5120
        int d = o >> 8, rem = o & 255;
        int h = rem >> 3, k4 = rem & 7;            // 4 k per u32
        const float* ws = wdis + d * 1024 + h;     // wdis[d][k][h]
        tab[ENCP_U32 + (d * 32 + h) * 8 + k4] =
            f32x4_to_fp8(ws[(k4 * 4 + 0) * 32] * 256.f,
                         ws[(k4 * 4 + 1) * 32] * 256.f,
                         ws[(k4 * 4 + 2) * 32] * 256.f,
                         ws[(k4 * 4 + 3) * 32] * 256.f);
    }
}

// ---------------- Kernel 2: fp8 MFMA, register indices, 4 waves/SIMD ----------------
// 512 blocks (2 i-rows = 128 cells) x 512 thr (8 waves), 2 blocks/CU ->
// 16 waves/CU. Wave owns one 16-cell tile. Indices in 30 VGPRs/lane (no sdx
// LDS). Per d: unpack idx (VALU), 3 LDS b64 gathers, 2 L1 B loads, 6 MFMAs.
__global__ void __launch_bounds__(512, 4)
main_kernel(const float* __restrict__ ab,      // (B,65,65)
            const int*   __restrict__ spos,    // (B,64,64)
            const int*   __restrict__ eidx,    // (B,64,64,20,3)
            const float* __restrict__ mask2d,  // (B,)
            const float* __restrict__ spw,     // (512,32)
            const float* __restrict__ tokw,    // (32,)
            const u32*   __restrict__ tab,     // [enc fp8 pad | Wd8] (ws)
            float*       __restrict__ out) {   // (B,32,65,65)
    extern __shared__ __align__(16) char dyn[];

    int tid = threadIdx.x, blk = blockIdx.x;   // 512 blocks
    int b = blk >> 5, i0 = (blk & 31) << 1;    // 2 i-rows

    int wv = tid >> 6, l = tid & 63;
    int c16 = l & 15, g = l >> 4;              // A row / B col, k-group
    int cellLoc = wv * 16 + c16;               // 0..127 (this lane's cell)

    // --- per-lane indices -> registers (4 g-lanes share a cell: bcast) ---
    const int* ep = eidx + ((size_t)blk * 128 + cellLoc) * 60;
    u32 w[30];
#pragma unroll
    for (int k = 0; k < 15; ++k) {
        v4i q = *(const v4i*)(ep + k * 4);     // 16B per lane, 16B-aligned
        w[2 * k]     = ((u32)q.x & 0xffffu) | ((u32)q.y << 16);
        w[2 * k + 1] = ((u32)q.z & 0xffffu) | ((u32)q.w << 16);
    }

    // --- stage padded enc fp8 into LDS (linear, L2-hot): 61,480 B ---
    {
        const u32x4* g4 = (const u32x4*)tab;
        u32x4* s4 = (u32x4*)dyn;
        for (int p = tid; p < 3842; p += 512) s4[p] = g4[p];
        if (tid < 2) ((u32*)dyn)[15368 + tid] = tab[15368 + tid];
    }
    __syncthreads();

    const char* encB = dyn + g * 8;            // + row*40 per gather
    const u32* wdg = tab + ENCP_U32;           // global fp8 Wd, L1-hot

    f32x4 acc[2][3] = {};                      // [head-half][f], static idx

#pragma unroll
    for (int d = 0; d < ND; ++d) {
        // indices p = 3d..3d+2, compile-time word/half selection
        u32 q0 = (w[(3 * d    ) >> 1] >> (((3 * d    ) & 1) * 16)) & 0xffffu;
        u32 q1 = (w[(3 * d + 1) >> 1] >> (((3 * d + 1) & 1) * 16)) & 0xffffu;
        u32 q2 = (w[(3 * d + 2) >> 1] >> (((3 * d + 2) & 1) * 16)) & 0xffffu;
        long bf0 = *(const long*)(wdg + (d * 32 + c16) * 8 + g * 2);
        long bf1 = *(const long*)(wdg + (d * 32 + c16 + 16) * 8 + g * 2);
        long a0 = *(const long*)(encB + q0 * 40u);
        long a1 = *(const long*)(encB + q1 * 40u);
        long a2 = *(const long*)(encB + q2 * 40u);
        acc[0][0] = __builtin_amdgcn_mfma_f32_16x16x32_fp8_fp8(a0, bf0, acc[0][0], 0, 0, 0);
        acc[1][0] = __builtin_amdgcn_mfma_f32_16x16x32_fp8_fp8(a0, bf1, acc[1][0], 0, 0, 0);
        acc[0][1] = __builtin_amdgcn_mfma_f32_16x16x32_fp8_fp8(a1, bf0, acc[0][1], 0, 0, 0);
        acc[1][1] = __builtin_amdgcn_mfma_f32_16x16x32_fp8_fp8(a1, bf1, acc[1][1], 0, 0, 0);
        acc[0][2] = __builtin_amdgcn_mfma_f32_16x16x32_fp8_fp8(a2, bf0, acc[0][2], 0, 0, 0);
        acc[1][2] = __builtin_amdgcn_mfma_f32_16x16x32_fp8_fp8(a2, bf1, acc[1][2], 0, 0, 0);
    }
    f32x4 acc0 = acc[0][0] + acc[0][1] + acc[0][2];
    f32x4 acc1 = acc[1][0] + acc[1][1] + acc[1][2];

    __syncthreads();                           // enc dead; alias comb over it
    float* comb = (float*)dyn;                 // [128 cells][33] = 16,896 B
    float m = mask2d[b];
#pragma unroll
    for (int r = 0; r < 4; ++r) {
        int cell = wv * 16 + g * 4 + r;        // D: row=(l>>4)*4+r, col=l&15
        int s = spos[blk * 128 + cell];        // L2-hot
        int sp = (s == 0) ? 1 : s;
        sp = (sp > 1) ? sp - 1 : sp;
        sp = (sp > ND) ? ND : sp;
        float esc = m / (196608.0f * (float)sp);   // /(256*256) /3sp
        float spbL = spw[s * NH + c16];
        float spbH = spw[s * NH + c16 + 16];
        comb[cell * 33 + c16]      = spbL * m + acc0[r] * esc;
        comb[cell * 33 + c16 + 16] = spbH * m + acc1[r] * esc;
    }
    __syncthreads();

    // --- write out: 2 rows x 32 h x 64 j, 256B-coalesced over j ---
#pragma unroll
    for (int w8 = 0; w8 < 8; ++w8) {
        int idx = w8 * 512 + tid;              // [0, 4096)
        int j = idx & 63, h = (idx >> 6) & 31, r = idx >> 11;
        float av = ab[(b * 65 + i0 + r + 1) * 65 + (j + 1)];
        __builtin_nontemporal_store(2.0f * av + comb[(r * 64 + j) * 33 + h],
            &out[(((size_t)b * NH + h) * 65 + i0 + r + 1) * 65 + (j + 1)]);
    }

    // --- borders (folded): col-0 of rows i0,i0+1; i0==0 block also row 0 ---
    if (tid < 2 * NH) {
        int r = tid >> 5, h = tid & 31;
        float av0 = ab[(b * 65 + i0 + r + 1) * 65];
        __builtin_nontemporal_store(2.0f * av0 + tokw[h],
            &out[(((size_t)b * NH + h) * 65 + i0 + r + 1) * 65 + 0]);
    }
    if (i0 == 0) {
        for (int t = tid; t < NH * 65; t += 512) {   // 2080 = 32h x 65j
            int h = t / 65, j = t - h * 65;
            __builtin_nontemporal_store(2.0f * ab[b * 4225 + j] + tokw[h],
                &out[(((size_t)b * NH + h) * 65 + 0) * 65 + j]);
        }
    }
}

extern "C" void kernel_launch(void* const* d_in, const int* in_sizes, int n_in,
                              void* d_out, int out_size, void* d_ws, size_t ws_size,
                              hipStream_t stream) {
    const float* attn_bias   = (const float*)d_in[0];
    const int*   spatial_pos = (const int*)  d_in[1];
    // d_in[2] = x (unused), d_in[4] = attn_edge_type (unused)
    const int*   edge_input  = (const int*)  d_in[3];
    const float* mask_2d     = (const float*)d_in[5];
    const float* edge_enc_w  = (const float*)d_in[6];
    const float* edge_dis_w  = (const float*)d_in[7];
    const float* spatial_w   = (const float*)d_in[8];
    const float* token_w     = (const float*)d_in[9];
    float* out = (float*)d_out;
    u32* tab = (u32*)d_ws;                 // 61,480 + 20,480 B

    // Kernel 1: fp8 converts only (69 blocks)
    prep_kernel<<<CVT1_BLOCKS + CVT2_BLOCKS, 256, 0, stream>>>(
        edge_enc_w, edge_dis_w, tab);
    // Kernel 2: fp8 MFMA, register indices (LDS = 61,480 B, 2 blocks/CU)
    main_kernel<<<512, 512, MAIN_LDS, stream>>>(attn_bias, spatial_pos, edge_input,
                                                mask_2d, spatial_w, token_w,
                                                tab, out);
}